// Round 4
// baseline (3837.594 us; speedup 1.0000x reference)
//
#include <hip/hip_runtime.h>

#define TT 512
#define XD 512
#define HH 1024
#define NGROUP 4
#define BLK_PER_G 64
#define GRP_DW 8192   // dwords per group h-buffer: 128 chunks * 16 rows * 4 dw

typedef __attribute__((ext_vector_type(8))) _Float16 h8;
typedef __attribute__((ext_vector_type(4))) float f4;
typedef __attribute__((ext_vector_type(4))) int i4;
typedef unsigned long long u64;

__device__ __forceinline__ float sigf(float x) { return 1.f / (1.f + __expf(-x)); }
__device__ __forceinline__ float tanhfast(float x) { return 1.f - 2.f / (__expf(2.f * x) + 1.f); }

__global__ __launch_bounds__(256, 1) void lstm_fused(
    const float* __restrict__ X,
    const float* __restrict__ Whi, const float* __restrict__ Wxi, const float* __restrict__ bi_p,
    const float* __restrict__ Whf, const float* __restrict__ Wxf, const float* __restrict__ bf_p,
    const float* __restrict__ Who, const float* __restrict__ Wxo, const float* __restrict__ bo_p,
    const float* __restrict__ Whz, const float* __restrict__ Wxz, const float* __restrict__ bz_p,
    float* __restrict__ out,
    int* __restrict__ flags,   // [NGROUP][BLK_PER_G]
    int* __restrict__ hxch)    // [2][NGROUP][GRP_DW] packed f16 h, A-frag chunk layout
{
    __shared__ f4 red[4][4][64];                     // [wave][gate][lane] partials, 16 KB
    __shared__ __align__(16) _Float16 sh16[16][16];  // epilogue pack staging
    __shared__ int stoken;                           // wave0 -> wave1 release token

    const int tid  = threadIdx.x;
    const int wave = tid >> 6;
    const int lane = tid & 63;
    const int ln   = lane & 15;   // N col (B/C frags) / M row (A frags)
    const int lq   = lane >> 4;   // quad 0..3

    const int blk = blockIdx.x;
    const int g   = blk & 3;      // group (batch slice) — R1-proven mapping
    const int j   = blk >> 2;     // 0..63 column-slice within group
    const int colbase = j * 16;
    const int rowbase = g * 16;
    const int col = colbase + ln;

    if (tid == 0) stoken = 0;

    const float* Wh[4]   = {Whi, Whf, Who, Whz};
    const float* Wx[4]   = {Wxi, Wxf, Wxo, Wxz};
    const float* bias[4] = {bi_p, bf_p, bo_p, bz_p};

    // ---- one-time: weights -> f16 B-fragments pinned in VGPRs ----
    h8 bh[4][8];   // Wh: this wave's K slice [wave*256, wave*256+256)
    h8 bx[4][4];   // Wx: this wave's K slice [wave*128, wave*128+128)
#pragma unroll
    for (int gi = 0; gi < 4; ++gi) {
        const float* W = Wh[gi];
#pragma unroll
        for (int kt = 0; kt < 8; ++kt) {
            const int k0 = wave * 256 + kt * 32 + lq * 8;
            h8 f;
#pragma unroll
            for (int q = 0; q < 8; ++q) f[q] = (_Float16)W[(k0 + q) * HH + col];
            bh[gi][kt] = f;
        }
        const float* Wq = Wx[gi];
#pragma unroll
        for (int kt = 0; kt < 4; ++kt) {
            const int k0 = wave * 128 + kt * 32 + lq * 8;
            h8 f;
#pragma unroll
            for (int q = 0; q < 8; ++q) f[q] = (_Float16)Wq[(k0 + q) * HH + col];
            bx[gi][kt] = f;
        }
    }
    float bsum[4];
#pragma unroll
    for (int gi = 0; gi < 4; ++gi) bsum[gi] = bias[gi][col];

    // epilogue row ownership (waves 0,1): 2 rows per lane
    const int m0 = (wave & 1) * 8 + lq * 2;
    const int m1 = m0 + 1;
    float cp0 = 0.f, cp1 = 0.f;

    const float* Xrow = X + (size_t)(rowbase + ln) * (TT * XD);
    const int gbase = g * GRP_DW;

    // poll target (loop-invariant): lanes 0..15 -> this wave's 16 producers
    // (one 64B line); lanes 16..63 -> own flag (guards red/buffer reuse).
    // Union over the 4 waves covers all 64 group flags -> exchange-buffer
    // double-buffer reuse stays safe (same argument as R1).
    const int* fp = flags + g * BLK_PER_G + ((lane < 16) ? (wave * 16 + lane) : j);

    // X prefetch registers (issued one step ahead; compiler tracks the waits)
    float4 xv[8];
    {
        const float* xb = Xrow + wave * 128;
#pragma unroll
        for (int kt = 0; kt < 4; ++kt) {
            const float4* xp = (const float4*)(xb + kt * 32 + lq * 8);
            xv[2 * kt] = xp[0]; xv[2 * kt + 1] = xp[1];
        }
    }
    __syncthreads();   // stoken init visible to all waves

    u64 hv[8][2];

    for (int t = 0; t < TT; ++t) {
        if (t > 0) {
            // group barrier: subset poll (proven agent-scope atomic loads)
            while (true) {
                int v = __hip_atomic_load(fp, __ATOMIC_RELAXED, __HIP_MEMORY_SCOPE_AGENT);
                if (__all(v >= t)) break;
                __builtin_amdgcn_s_sleep(1);
            }
            // issue h_{t-1} loads immediately (x-MFMAs below fill the shadow)
            const int rb = ((t - 1) & 1) * (NGROUP * GRP_DW) + gbase;
#pragma unroll
            for (int kt = 0; kt < 8; ++kt) {
                const u64* hp = (const u64*)(hxch + rb + ((wave * 32 + kt * 4 + lq) * 16 + ln) * 4);
                hv[kt][0] = __hip_atomic_load(hp + 0, __ATOMIC_RELAXED, __HIP_MEMORY_SCOPE_AGENT);
                hv[kt][1] = __hip_atomic_load(hp + 1, __ATOMIC_RELAXED, __HIP_MEMORY_SCOPE_AGENT);
            }
        }

        // ---- x-part from prefetched registers (runs under h-load latency) ----
        f4 acc[4];
#pragma unroll
        for (int gi = 0; gi < 4; ++gi) acc[gi] = (f4){0.f, 0.f, 0.f, 0.f};

        h8 ax[4];
#pragma unroll
        for (int kt = 0; kt < 4; ++kt) {
            float4 a = xv[2 * kt], b2 = xv[2 * kt + 1];
            h8 f;
            f[0] = (_Float16)a.x;  f[1] = (_Float16)a.y;
            f[2] = (_Float16)a.z;  f[3] = (_Float16)a.w;
            f[4] = (_Float16)b2.x; f[5] = (_Float16)b2.y;
            f[6] = (_Float16)b2.z; f[7] = (_Float16)b2.w;
            ax[kt] = f;
        }
#pragma unroll
        for (int kt = 0; kt < 4; ++kt)
#pragma unroll
            for (int gi = 0; gi < 4; ++gi)
                acc[gi] = __builtin_amdgcn_mfma_f32_16x16x32_f16(ax[kt], bx[gi][kt], acc[gi], 0, 0, 0);

        if (t > 0) {
#pragma unroll
            for (int kt = 0; kt < 8; ++kt) {
                union { u64 u[2]; h8 f; } uu;
                uu.u[0] = hv[kt][0]; uu.u[1] = hv[kt][1];
#pragma unroll
                for (int gi = 0; gi < 4; ++gi)
                    acc[gi] = __builtin_amdgcn_mfma_f32_16x16x32_f16(uu.f, bh[gi][kt], acc[gi], 0, 0, 0);
            }
        }

        // ---- stage partials (ALL 4 waves; epilogue needs cross-lane access) ----
#pragma unroll
        for (int gi = 0; gi < 4; ++gi) red[wave][gi][lane] = acc[gi];

        // waves 2,3: prefetch X for t+1 now (latency hidden by their next poll)
        if (wave >= 2 && t < TT - 1) {
            const float* xb = Xrow + (t + 1) * XD + wave * 128;
#pragma unroll
            for (int kt = 0; kt < 4; ++kt) {
                const float4* xp = (const float4*)(xb + kt * 32 + lq * 8);
                xv[2 * kt] = xp[0]; xv[2 * kt + 1] = xp[1];
            }
        }
        __syncthreads();

        // ---- split epilogue: wave0 rows 0..7, wave1 rows 8..15 ----
        if (wave < 2) {
            const int lqp = m0 >> 2;          // source quad
            const int sl  = lqp * 16 + ln;    // source lane in red
            const int e0  = m0 & 3;           // element offset (0 or 2)
            float ga[4], gb[4];
#pragma unroll
            for (int gi = 0; gi < 4; ++gi) {
                float s0 = bsum[gi], s1 = bsum[gi];
#pragma unroll
                for (int wv = 0; wv < 4; ++wv) {
                    const float* rp = (const float*)&red[wv][gi][sl];
                    float2 p = *(const float2*)(rp + e0);
                    s0 += p.x; s1 += p.y;
                }
                ga[gi] = s0; gb[gi] = s1;
            }
            float i0 = sigf(ga[0]), f0 = sigf(ga[1]), o0 = sigf(ga[2]), z0 = tanhfast(ga[3]);
            float c0 = i0 * z0 + f0 * cp0; cp0 = c0;
            float h0 = o0 * tanhfast(c0);
            float i1 = sigf(gb[0]), f1 = sigf(gb[1]), o1 = sigf(gb[2]), z1 = tanhfast(gb[3]);
            float c1 = i1 * z1 + f1 * cp1; cp1 = c1;
            float h1 = o1 * tanhfast(c1);

            sh16[m0][ln] = (_Float16)h0;
            sh16[m1][ln] = (_Float16)h1;

            asm volatile("s_waitcnt lgkmcnt(0)" ::: "memory");
            // pack own 8 rows into A-frag chunk layout (no cross-wave LDS dep)
            if (lane < 16) {
                const int half2 = lane >> 3;
                const int row   = (wave & 1) * 8 + (lane & 7);
                i4 pk = *(const i4*)&sh16[row][half2 * 8];
                int* wp = hxch + (t & 1) * (NGROUP * GRP_DW) + gbase
                        + ((2 * j + half2) * 16 + row) * 4;
                union { i4 v; u64 u[2]; } pu; pu.v = pk;
                __hip_atomic_store((u64*)wp,     pu.u[0], __ATOMIC_RELAXED, __HIP_MEMORY_SCOPE_AGENT);
                __hip_atomic_store((u64*)wp + 1, pu.u[1], __ATOMIC_RELAXED, __HIP_MEMORY_SCOPE_AGENT);
            }
            // release chain: each wave drains its own pack stores; wave0
            // passes a token through LDS; wave1 publishes the single flag.
            asm volatile("s_waitcnt vmcnt(0)" ::: "memory");
            if (wave == 0) {
                *(volatile int*)&stoken = t + 1;
            } else {
                while (*(volatile int*)&stoken < t + 1) {}
                if (lane == 0)
                    __hip_atomic_store(&flags[g * BLK_PER_G + j], t + 1,
                                       __ATOMIC_RELAXED, __HIP_MEMORY_SCOPE_AGENT);
            }
            asm volatile("" ::: "memory");   // keep out-stores below the flag

            // f32 result stores — off the critical path
            out[(size_t)(rowbase + m0) * (TT * HH) + (size_t)t * HH + col] = h0;
            out[(size_t)(rowbase + m1) * (TT * HH) + (size_t)t * HH + col] = h1;

            // prefetch X for t+1 (after the release drain, so it never
            // lengthens the publish path; hidden under the next poll)
            if (t < TT - 1) {
                const float* xb = Xrow + (t + 1) * XD + wave * 128;
#pragma unroll
                for (int kt = 0; kt < 4; ++kt) {
                    const float4* xp = (const float4*)(xb + kt * 32 + lq * 8);
                    xv[2 * kt] = xp[0]; xv[2 * kt + 1] = xp[1];
                }
            }
        }
        // Buffer reuse: block b writes hxch buf[t&1] at t only after all 4
        // waves passed poll(t) (union = all 64 flags >= t), i.e. every block
        // finished reading buf[t&1] (= h_{t-2}) during step t-1.  `red`
        // overwrite at t+1 is gated by own-flag >= t+1, which the token
        // chain orders after BOTH epilogue waves' red reads at t.
    }
}

extern "C" void kernel_launch(void* const* d_in, const int* in_sizes, int n_in,
                              void* d_out, int out_size, void* d_ws, size_t ws_size,
                              hipStream_t stream) {
    const float* X   = (const float*)d_in[0];
    const float* Whi = (const float*)d_in[1];
    const float* Wxi = (const float*)d_in[2];
    const float* bi  = (const float*)d_in[3];
    const float* Whf = (const float*)d_in[4];
    const float* Wxf = (const float*)d_in[5];
    const float* bf  = (const float*)d_in[6];
    const float* Who = (const float*)d_in[7];
    const float* Wxo = (const float*)d_in[8];
    const float* bo  = (const float*)d_in[9];
    const float* Whz = (const float*)d_in[10];
    const float* Wxz = (const float*)d_in[11];
    const float* bz  = (const float*)d_in[12];
    float* out = (float*)d_out;

    int* flags = (int*)d_ws;            // NGROUP*BLK_PER_G ints = 1 KB
    int* hxch  = flags + 256;           // 2 buffers * 4 groups * 32 KB = 256 KB
    hipMemsetAsync(d_ws, 0, NGROUP * BLK_PER_G * sizeof(int), stream);

    // 256 blocks, 1 block/CU on 256 CUs -> co-residency by capacity
    // (guaranteed for any VGPR count at 256 threads); R1-proven geometry.
    lstm_fused<<<dim3(256), dim3(256), 0, stream>>>(
        X, Whi, Wxi, bi, Whf, Wxf, bf, Who, Wxo, bo, Whz, Wxz, bz, out, flags, hxch);
}